// Round 4
// baseline (551.716 us; speedup 1.0000x reference)
//
#include <hip/hip_runtime.h>
#include <hip/hip_bf16.h>

typedef __bf16 bf8_t __attribute__((ext_vector_type(8)));
typedef float f4_t __attribute__((ext_vector_type(4)));

#define B_ 32
#define T_ 2048
#define C_ 1024
#define H_ 128

// async global->LDS DMA, 16B per lane, lands at ldsbase + lane*16
__device__ __forceinline__ void async16(const void* g, void* l) {
    __builtin_amdgcn_global_load_lds(
        (const __attribute__((address_space(1))) void*)g,
        (__attribute__((address_space(3))) void*)l, 16, 0, 0);
}

// ---------------- W fp32 -> bf16 once: Wb = [K;Q;V] as [384][1024] -----------
__global__ __launch_bounds__(256) void wconv_kernel(
    const float* __restrict__ Wk, const float* __restrict__ Wq, const float* __restrict__ Wv,
    __bf16* __restrict__ Wb)
{
    const int e = (blockIdx.x * 256 + threadIdx.x) * 8;
    const int arr = e >> 17;
    const int off = e & 131071;
    const float* W = (arr == 0) ? Wk : (arr == 1) ? Wq : Wv;
    float4 f0 = *(const float4*)(W + off);
    float4 f1 = *(const float4*)(W + off + 4);
    bf8_t o;
    o[0] = (__bf16)f0.x; o[1] = (__bf16)f0.y; o[2] = (__bf16)f0.z; o[3] = (__bf16)f0.w;
    o[4] = (__bf16)f1.x; o[5] = (__bf16)f1.y; o[6] = (__bf16)f1.z; o[7] = (__bf16)f1.w;
    *(bf8_t*)(Wb + e) = o;
}

// ---------------- fused projection: DMA fragment-order staging ----------------
// grid 1024, block 256 (4 waves). Tile M=64 x N=384 (K|Q|V), BK=32.
// LDS holds tiles in MFMA-fragment order: DMA lane L's global address is the
// 16B chunk lane L reads back at base+L*16 -> stride-1 ds_read_b128, 0 conflicts.
__global__ __launch_bounds__(256, 3) void proj_kernel(
    const float* __restrict__ x, const __bf16* __restrict__ Wb,
    __bf16* __restrict__ Kb, __bf16* __restrict__ Qb, __bf16* __restrict__ VtG)
{
    __shared__ __align__(16) float  Xf[4][2][64][4];   // [mi][chunk][lane][4 fp32]  8 KB
    __shared__ __align__(16) __bf16 Wf[6][4][64][8];   // [ni][wn][lane][8 bf16]    24 KB

    const int m0   = blockIdx.x * 64;
    const int tid  = threadIdx.x;
    const int lane = tid & 63;
    const int wn   = tid >> 6;
    const int lr   = lane & 15;
    const int quad = lane >> 4;

    f4_t acc[4][6];
    #pragma unroll
    for (int mi = 0; mi < 4; mi++)
        for (int ni = 0; ni < 6; ni++) acc[mi][ni] = f4_t{0.f, 0.f, 0.f, 0.f};

    for (int kk = 0; kk < C_; kk += 32) {
        // issue DMA: wave wn stages X rows wn*16.. (mi=wn) and its own W fragments
        #pragma unroll
        for (int c = 0; c < 2; c++)
            async16(x + (size_t)(m0 + wn * 16 + lr) * C_ + kk + quad * 8 + c * 4,
                    &Xf[wn][c][lane][0]);
        #pragma unroll
        for (int ni = 0; ni < 6; ni++)
            async16(Wb + (size_t)(ni * 64 + wn * 16 + lr) * C_ + kk + quad * 8,
                    &Wf[ni][wn][lane][0]);
        __syncthreads();   // drains vmcnt -> tiles ready

        bf8_t xa[4];
        #pragma unroll
        for (int mi = 0; mi < 4; mi++) {
            float4 a0 = *(const float4*)&Xf[mi][0][lane][0];
            float4 a1 = *(const float4*)&Xf[mi][1][lane][0];
            bf8_t t;
            t[0] = (__bf16)a0.x; t[1] = (__bf16)a0.y; t[2] = (__bf16)a0.z; t[3] = (__bf16)a0.w;
            t[4] = (__bf16)a1.x; t[5] = (__bf16)a1.y; t[6] = (__bf16)a1.z; t[7] = (__bf16)a1.w;
            xa[mi] = t;
        }
        #pragma unroll
        for (int ni = 0; ni < 6; ni++) {
            bf8_t wb = *(const bf8_t*)&Wf[ni][wn][lane][0];
            if (ni < 4) {
                #pragma unroll
                for (int mi = 0; mi < 4; mi++)
                    acc[mi][ni] = __builtin_amdgcn_mfma_f32_16x16x32_bf16(xa[mi], wb, acc[mi][ni], 0, 0, 0);
            } else {
                // V transposed: D' = W * X^T (swapped operands)
                #pragma unroll
                for (int mi = 0; mi < 4; mi++)
                    acc[mi][ni] = __builtin_amdgcn_mfma_f32_16x16x32_bf16(wb, xa[mi], acc[mi][ni], 0, 0, 0);
            }
        }
        __syncthreads();   // all reads done before next iter's DMA overwrites
    }

    const int bb = m0 >> 11;
    const int t0 = m0 & (T_ - 1);
    #pragma unroll
    for (int ni = 0; ni < 4; ni++) {
        __bf16* Out = (ni < 2) ? Kb : Qb;
        const int col = (ni & 1) * 64 + wn * 16 + lr;
        #pragma unroll
        for (int mi = 0; mi < 4; mi++)
            for (int r = 0; r < 4; r++) {
                const int row = m0 + mi * 16 + quad * 4 + r;
                Out[(size_t)row * H_ + col] = (__bf16)acc[mi][ni][r];
            }
    }
    #pragma unroll
    for (int ni = 4; ni < 6; ni++)
        for (int mi = 0; mi < 4; mi++) {
            const int tok = t0 + mi * 16 + lr;
            #pragma unroll
            for (int r = 0; r < 4; r++) {
                const int h = (ni - 4) * 64 + wn * 16 + quad * 4 + r;
                VtG[(size_t)bb * H_ * T_ + (size_t)h * T_ + tok] = (__bf16)acc[mi][ni][r];
            }
        }
}

// ---------------- flash attention: DMA fragment-order K/Vt staging -----------
// grid (16, 32), block 512 (8 waves). Q-tile 128; wave w owns rows w*16..+15.
// K/Vt staged by global_load_lds directly in B-fragment order (0 conflicts).
__global__ __launch_bounds__(512, 4) void flash_kernel(
    const __bf16* __restrict__ Qb, const __bf16* __restrict__ Kb,
    const __bf16* __restrict__ VtG, float* __restrict__ Out)
{
    __shared__ __align__(16) __bf16 Kf[4][4][64][8];   // [n][ks][lane][8]  16 KB
    __shared__ __align__(16) __bf16 Vf[8][2][64][8];   // [n][ks][lane][8]  16 KB
    __shared__ __bf16 Ps[128][72];                     // padded, wave-private slabs

    const int qt = (blockIdx.y < 16) ? (15 - blockIdx.x) : blockIdx.x;   // balance
    const int b  = blockIdx.y;
    const size_t kqbase = (size_t)b * T_ * H_;
    const size_t vbase  = (size_t)b * H_ * T_;

    const int tid  = threadIdx.x;
    const int lane = tid & 63;
    const int w    = tid >> 6;
    const int lr   = lane & 15;
    const int quad = lane >> 4;

    bf8_t qf[4];
    {
        const __bf16* qp = Qb + kqbase + (size_t)(qt * 128 + w * 16 + lr) * H_ + quad * 8;
        #pragma unroll
        for (int ks = 0; ks < 4; ks++) qf[ks] = *(const bf8_t*)(qp + ks * 32);
    }

    f4_t o[8];
    #pragma unroll
    for (int n = 0; n < 8; n++) o[n] = f4_t{0.f, 0.f, 0.f, 0.f};
    float ls[4] = {0.f, 0.f, 0.f, 0.f};

    const float sc = 0.03125f * 1.4426950408889634f;   // C^-0.5 * log2(e)
    const int jmax = 2 * qt + 1;

    for (int j = 0; j <= jmax; j++) {
        const int s0 = j * 64;
        // issue DMA: 32 instrs/block, 4 per wave (wave-uniform f -> uniform LDS base)
        #pragma unroll
        for (int i = 0; i < 4; i++) {
            const int f = w * 4 + i;
            if (f < 16) {
                const int n = f >> 2, ks = f & 3;
                async16(Kb + kqbase + (size_t)(s0 + n * 16 + lr) * H_ + ks * 32 + quad * 8,
                        &Kf[n][ks][lane][0]);
            } else {
                const int g = f - 16, n = g >> 1, ks = g & 1;
                async16(VtG + vbase + (size_t)(n * 16 + lr) * T_ + s0 + ks * 32 + quad * 8,
                        &Vf[n][ks][lane][0]);
            }
        }
        __syncthreads();   // drain DMA

        const bool skip = (j == jmax && w < 4);   // fully-masked waves
        if (!skip) {
            f4_t s4[4];
            #pragma unroll
            for (int n = 0; n < 4; n++) s4[n] = f4_t{0.f, 0.f, 0.f, 0.f};
            #pragma unroll
            for (int ks = 0; ks < 4; ks++)
                for (int n = 0; n < 4; n++) {
                    bf8_t kf = *(const bf8_t*)&Kf[n][ks][lane][0];
                    s4[n] = __builtin_amdgcn_mfma_f32_16x16x32_bf16(qf[ks], kf, s4[n], 0, 0, 0);
                }

            const bool domask = (j - 2 * qt) == (w >> 2);
            const int rowg = qt * 128 + w * 16 + quad * 4;
            #pragma unroll
            for (int n = 0; n < 4; n++) {
                const int colg = s0 + n * 16 + lr;
                #pragma unroll
                for (int r = 0; r < 4; r++) {
                    float p = __builtin_exp2f(s4[n][r] * sc);
                    if (domask && colg > rowg + r) p = 0.f;
                    ls[r] += p;
                    Ps[w * 16 + quad * 4 + r][n * 16 + lr] = (__bf16)p;
                }
            }

            #pragma unroll
            for (int ks = 0; ks < 2; ks++) {
                bf8_t pf = *(const bf8_t*)&Ps[w * 16 + lr][ks * 32 + quad * 8];
                #pragma unroll
                for (int n = 0; n < 8; n++) {
                    bf8_t vf = *(const bf8_t*)&Vf[n][ks][lane][0];
                    o[n] = __builtin_amdgcn_mfma_f32_16x16x32_bf16(pf, vf, o[n], 0, 0, 0);
                }
            }
        }
        __syncthreads();   // reads done before next iter's DMA
    }

    float inv[4];
    #pragma unroll
    for (int r = 0; r < 4; r++) {
        float v = ls[r];
        v += __shfl_xor(v, 1);
        v += __shfl_xor(v, 2);
        v += __shfl_xor(v, 4);
        v += __shfl_xor(v, 8);
        inv[r] = 1.f / v;
    }
    #pragma unroll
    for (int n = 0; n < 8; n++) {
        const int col = n * 16 + lr;
        #pragma unroll
        for (int r = 0; r < 4; r++) {
            const int row = qt * 128 + w * 16 + quad * 4 + r;
            Out[kqbase + (size_t)row * H_ + col] = o[n][r] * inv[r];
        }
    }
}

extern "C" void kernel_launch(void* const* d_in, const int* in_sizes, int n_in,
                              void* d_out, int out_size, void* d_ws, size_t ws_size,
                              hipStream_t stream) {
    const float* x  = (const float*)d_in[0];
    const float* Wk = (const float*)d_in[1];
    const float* Wq = (const float*)d_in[2];
    const float* Wv = (const float*)d_in[3];
    float* out = (float*)d_out;

    const size_t n_kqv = (size_t)B_ * T_ * H_;
    __bf16* Kb  = (__bf16*)d_ws;
    __bf16* Qb  = Kb + n_kqv;
    __bf16* VtG = Qb + n_kqv;
    __bf16* Wb  = VtG + n_kqv;

    wconv_kernel<<<dim3(192), 256, 0, stream>>>(Wk, Wq, Wv, Wb);
    proj_kernel<<<dim3((B_ * T_) / 64), 256, 0, stream>>>(x, Wb, Kb, Qb, VtG);
    flash_kernel<<<dim3(16, B_), 512, 0, stream>>>(Qb, Kb, VtG, out);
}